// Round 15
// baseline (648.994 us; speedup 1.0000x reference)
//
#include <hip/hip_runtime.h>

typedef _Float16 f16;
typedef unsigned short u16;
typedef unsigned int u32;
typedef long long i64;
typedef __attribute__((ext_vector_type(8))) _Float16 f16x8;
typedef __attribute__((ext_vector_type(4))) float f32x4;

#define IN_F 4096
#define OUT_F 4096

__device__ __forceinline__ void gload16(const f16* g, f16* l) {
  __builtin_amdgcn_global_load_lds(
      (const __attribute__((address_space(1))) void*)g,
      (__attribute__((address_space(3))) void*)l, 16, 0, 0);
}

// ---------------------------------------------------------------------------
// prep kernels
// ---------------------------------------------------------------------------
__global__ __launch_bounds__(256) void cvt_f32_f16(
    const float* __restrict__ in, f16* __restrict__ out, i64 n8) {
  i64 s = (i64)gridDim.x * blockDim.x;
  for (i64 j = (i64)blockIdx.x * blockDim.x + threadIdx.x; j < n8; j += s) {
    float4 a = ((const float4*)in)[2 * j];
    float4 b = ((const float4*)in)[2 * j + 1];
    f16x8 o;
    o[0] = (f16)a.x; o[1] = (f16)a.y; o[2] = (f16)a.z; o[3] = (f16)a.w;
    o[4] = (f16)b.x; o[5] = (f16)b.y; o[6] = (f16)b.z; o[7] = (f16)b.w;
    ((f16x8*)out)[j] = o;
  }
}

__global__ __launch_bounds__(256) void zero32(u32* __restrict__ p, i64 n) {
  i64 s = (i64)gridDim.x * blockDim.x;
  for (i64 j = (i64)blockIdx.x * blockDim.x + threadIdx.x; j < n; j += s) p[j] = 0u;
}

__global__ __launch_bounds__(256) void scatter_woh(
    const float* __restrict__ vals, const int* __restrict__ rows,
    const int* __restrict__ cols, f16* __restrict__ woh, int nnz) {
  int i = blockIdx.x * blockDim.x + threadIdx.x;
  if (i >= nnz) return;
  int r = rows[i], c = cols[i];
  if (r < 0 || r >= OUT_F || c < 0 || c >= IN_F) return;
  float v = vals[i];
  size_t idx = (size_t)r * IN_F + c;
  u32* p = (u32*)woh + (idx >> 1);
  u32 sh = (u32)(idx & 1) * 16u;
  union { f16 h; u16 u; } cv;
  u32 old = *p;
  while (true) {
    u32 assumed = old;
    cv.u = (u16)((assumed >> sh) & 0xFFFFu);
    float cur = (float)cv.h;
    cv.h = (f16)(cur + v);
    u32 nw = (assumed & ~(0xFFFFu << sh)) | ((u32)cv.u << sh);
    old = atomicCAS(p, assumed, nw);
    if (old == assumed) break;
  }
}

// ---------------------------------------------------------------------------
// 256x256 tile, BK=64, 16 waves (1024 thr, 4x4 quadrants of 64x64).
// acc[4][4] = 64 regs/wave -> 4 waves/SIMD (2x TLP of the 8-wave version).
// T2 swizzle (pre-swizzled global src, lane-linear LDS dest), 4 phases/tile
// x 8 MFMA, stages issued ph1-2 (youngest >=2 phases old at boundary drain),
// T5 setprio.  STREAM 0: out = f32(f16(acc));  1: out += acc.
// ---------------------------------------------------------------------------
template <int STREAM>
__global__ __launch_bounds__(1024, 4) void gemm_1k(
    const f16* __restrict__ Xh, const f16* __restrict__ Bm,
    float* __restrict__ out, int M) {
  __shared__ alignas(16) f16 As[2][16384];
  __shared__ alignas(16) f16 Bs[2][16384];

  const int tid = threadIdx.x;
  const int lane = tid & 63;
  const int wave = tid >> 6;        // 0..15
  const int wr = wave >> 2;         // 0..3 (M quarter)
  const int wc = wave & 3;          // 0..3 (N quarter)
  const int lo = lane & 15, hi = lane >> 4, l7 = lane & 7;

  const int bid = (int)blockIdx.x;
  const int nbn = OUT_F / 256;                      // 16
  const int nwg = (M / 256) * nbn;
  const int swz = ((nwg & 7) == 0) ? ((bid & 7) * (nwg >> 3) + (bid >> 3)) : bid;
  const int brow = (swz / nbn) << 8;
  const int bcol = (swz % nbn) << 8;

  // staging: 2 chunks per matrix per thread: c = tid (rows 0-127, "h0"),
  // c = tid+1024 (rows 128-255, "h1"). LDS dest lane-linear c*8; global src
  // row = c>>3, kchunk = (c&7)^(row&7)  [T2 pre-swizzle; (row+128)&7 == row&7]
  const int row0 = tid >> 3;
  const int kc0  = (tid & 7) ^ (row0 & 7);
  const int ldst = tid * 8;
  const i64 ag = (i64)(brow + row0) * IN_F + kc0 * 8;
  const i64 bg = (i64)(bcol + row0) * IN_F + kc0 * 8;
  const i64 hstep = (i64)128 * IN_F;

  // fragment reads: row*64 + (((ks<<2)|hi) ^ (row&7))*8;  row&7 == l7
  const int abase = (wr * 64 + lo) * 64;    // + mf*1024 + slot
  const int bbase = (wc * 64 + lo) * 64;    // + nf*1024 + slot
  const int slot0 = (hi ^ l7) * 8;          // ks=0
  const int slot1 = ((4 + hi) ^ l7) * 8;    // ks=1

  f32x4 acc[4][4] = {};

  // prologue: tile 0 -> buf 0
  gload16(Xh + ag, &As[0][ldst]);
  gload16(Bm + bg, &Bs[0][ldst]);
  gload16(Xh + ag + hstep, &As[0][ldst + 8192]);
  gload16(Bm + bg + hstep, &Bs[0][ldst + 8192]);
  asm volatile("s_waitcnt vmcnt(0)" ::: "memory");
  __builtin_amdgcn_sched_barrier(0);
  __builtin_amdgcn_s_barrier();

  const int NT = IN_F / 64;                 // 64
  for (int kt = 0; kt < NT; ++kt) {
    const f16* A = As[kt & 1];
    const f16* B = Bs[kt & 1];
    f16* An = (f16*)As[(kt & 1) ^ 1];
    f16* Bn = (f16*)Bs[(kt & 1) ^ 1];
    const int kn = (kt + 1) * 64;
    const bool pf = (kt + 1 < NT);

    f16x8 bf[4][2], af[2];

    // ---- phase 1: read bf all + af(mf0) | stage A-h0, B-h0 of kt+1
#pragma unroll
    for (int nf = 0; nf < 4; ++nf) {
      bf[nf][0] = *(const f16x8*)(B + bbase + nf * 1024 + slot0);
      bf[nf][1] = *(const f16x8*)(B + bbase + nf * 1024 + slot1);
    }
    af[0] = *(const f16x8*)(A + abase + 0 * 1024 + slot0);
    af[1] = *(const f16x8*)(A + abase + 0 * 1024 + slot1);
    if (pf) { gload16(Xh + ag + kn, An + ldst);
              gload16(Bm + bg + kn, Bn + ldst); }
    __builtin_amdgcn_s_barrier();
    __builtin_amdgcn_s_setprio(1);
#pragma unroll
    for (int nf = 0; nf < 4; ++nf) {
      acc[0][nf] = __builtin_amdgcn_mfma_f32_16x16x32_f16(af[0], bf[nf][0], acc[0][nf], 0, 0, 0);
      acc[0][nf] = __builtin_amdgcn_mfma_f32_16x16x32_f16(af[1], bf[nf][1], acc[0][nf], 0, 0, 0);
    }
    __builtin_amdgcn_s_setprio(0);
    __builtin_amdgcn_s_barrier();

    // ---- phase 2: af(mf1) | stage A-h1, B-h1 of kt+1
    af[0] = *(const f16x8*)(A + abase + 1 * 1024 + slot0);
    af[1] = *(const f16x8*)(A + abase + 1 * 1024 + slot1);
    if (pf) { gload16(Xh + ag + hstep + kn, An + ldst + 8192);
              gload16(Bm + bg + hstep + kn, Bn + ldst + 8192); }
    __builtin_amdgcn_s_barrier();
    __builtin_amdgcn_s_setprio(1);
#pragma unroll
    for (int nf = 0; nf < 4; ++nf) {
      acc[1][nf] = __builtin_amdgcn_mfma_f32_16x16x32_f16(af[0], bf[nf][0], acc[1][nf], 0, 0, 0);
      acc[1][nf] = __builtin_amdgcn_mfma_f32_16x16x32_f16(af[1], bf[nf][1], acc[1][nf], 0, 0, 0);
    }
    __builtin_amdgcn_s_setprio(0);
    __builtin_amdgcn_s_barrier();

    // ---- phase 3: af(mf2)
    af[0] = *(const f16x8*)(A + abase + 2 * 1024 + slot0);
    af[1] = *(const f16x8*)(A + abase + 2 * 1024 + slot1);
    __builtin_amdgcn_s_barrier();
    __builtin_amdgcn_s_setprio(1);
#pragma unroll
    for (int nf = 0; nf < 4; ++nf) {
      acc[2][nf] = __builtin_amdgcn_mfma_f32_16x16x32_f16(af[0], bf[nf][0], acc[2][nf], 0, 0, 0);
      acc[2][nf] = __builtin_amdgcn_mfma_f32_16x16x32_f16(af[1], bf[nf][1], acc[2][nf], 0, 0, 0);
    }
    __builtin_amdgcn_s_setprio(0);
    __builtin_amdgcn_s_barrier();

    // ---- phase 4: af(mf3) | boundary drain (youngest stage is 2 phases old)
    af[0] = *(const f16x8*)(A + abase + 3 * 1024 + slot0);
    af[1] = *(const f16x8*)(A + abase + 3 * 1024 + slot1);
    __builtin_amdgcn_s_barrier();
    __builtin_amdgcn_s_setprio(1);
#pragma unroll
    for (int nf = 0; nf < 4; ++nf) {
      acc[3][nf] = __builtin_amdgcn_mfma_f32_16x16x32_f16(af[0], bf[nf][0], acc[3][nf], 0, 0, 0);
      acc[3][nf] = __builtin_amdgcn_mfma_f32_16x16x32_f16(af[1], bf[nf][1], acc[3][nf], 0, 0, 0);
    }
    __builtin_amdgcn_s_setprio(0);
    if (pf) {
      asm volatile("s_waitcnt vmcnt(0)" ::: "memory");
      __builtin_amdgcn_sched_barrier(0);
    }
    __builtin_amdgcn_s_barrier();
  }

  // epilogue.  C/D: col = lane&15, row = (lane>>4)*4 + r  (m89-verified)
  const int crow0 = brow + wr * 64 + (hi << 2);
  const int ccol0 = bcol + wc * 64 + lo;
#pragma unroll
  for (int mf = 0; mf < 4; ++mf)
#pragma unroll
    for (int nf = 0; nf < 4; ++nf)
#pragma unroll
      for (int r = 0; r < 4; ++r) {
        float* p = out + (size_t)(crow0 + mf * 16 + r) * OUT_F + (ccol0 + nf * 16);
        if constexpr (STREAM == 0)
          *p = (float)(f16)acc[mf][nf][r];
        else
          *p += acc[mf][nf][r];
      }
}

// ---------------------------------------------------------------------------
// R12 fallback (proven): 128x128, 2-barrier, reg-staged A from f32
// ---------------------------------------------------------------------------
template <bool A16, int STREAM>
__global__ __launch_bounds__(256, 2) void gemm_one(
    const float* __restrict__ Xf, const f16* __restrict__ Xh,
    const f16* __restrict__ Bm, float* __restrict__ out, int M) {
  constexpr int LDA = A16 ? 32 : 40;
  __shared__ alignas(16) f16 As[128 * LDA];
  __shared__ alignas(16) f16 Bs[128 * 32];

  const int tid = threadIdx.x, lane = tid & 63, wave = tid >> 6;
  const int wr = wave >> 1, wc = wave & 1;
  const int nbn = OUT_F / 128;
  const int nwg = (int)gridDim.x;
  const int bid = (int)blockIdx.x;
  const int swz = ((nwg & 7) == 0) ? ((bid & 7) * (nwg >> 3) + (bid >> 3)) : bid;
  const int brow = (swz / nbn) << 7;
  const int bcol = (swz % nbn) << 7;

  f32x4 acc[4][4] = {};
  const int srow = tid >> 2, sk = (tid & 3) * 8;
  const f16* gB = Bm + (size_t)(bcol + srow) * IN_F + sk;
  f16* sB = Bs + tid * 8;
  const f16*   gA = A16 ? (Xh + (size_t)(brow + srow) * IN_F + sk) : (const f16*)nullptr;
  const float* gX = A16 ? (const float*)nullptr : (Xf + (size_t)(brow + srow) * IN_F + sk);
  f16* sA  = As + tid * 8;
  f16* sAr = As + srow * LDA + sk;
  const f16* pa = As + (wr * 64 + (lane & 15)) * LDA + (lane >> 4) * 8;
  const f16* pb = Bs + (wc * 64 + (lane & 15)) * 32 + (lane >> 4) * 8;

  for (int k0 = 0; k0 < IN_F; k0 += 32) {
    if constexpr (A16) {
      gload16(gA + k0, sA);
      gload16(gA + k0 + (size_t)64 * IN_F, sA + 2048);
    } else {
      float4 u0 = *(const float4*)(gX + k0);
      float4 u1 = *(const float4*)(gX + k0 + 4);
      float4 v0 = *(const float4*)(gX + k0 + (size_t)64 * IN_F);
      float4 v1 = *(const float4*)(gX + k0 + (size_t)64 * IN_F + 4);
      f16x8 h0, h1;
      h0[0] = (f16)u0.x; h0[1] = (f16)u0.y; h0[2] = (f16)u0.z; h0[3] = (f16)u0.w;
      h0[4] = (f16)u1.x; h0[5] = (f16)u1.y; h0[6] = (f16)u1.z; h0[7] = (f16)u1.w;
      h1[0] = (f16)v0.x; h1[1] = (f16)v0.y; h1[2] = (f16)v0.z; h1[3] = (f16)v0.w;
      h1[4] = (f16)v1.x; h1[5] = (f16)v1.y; h1[6] = (f16)v1.z; h1[7] = (f16)v1.w;
      *(f16x8*)sAr = h0;
      *(f16x8*)(sAr + 64 * LDA) = h1;
    }
    gload16(gB + k0, sB);
    gload16(gB + k0 + (size_t)64 * IN_F, sB + 2048);
    __syncthreads();
    f16x8 af[4], bfr[4];
#pragma unroll
    for (int m = 0; m < 4; ++m) af[m] = *(const f16x8*)(pa + m * 16 * LDA);
#pragma unroll
    for (int n = 0; n < 4; ++n) bfr[n] = *(const f16x8*)(pb + n * 512);
#pragma unroll
    for (int m = 0; m < 4; ++m)
#pragma unroll
      for (int n = 0; n < 4; ++n)
        acc[m][n] = __builtin_amdgcn_mfma_f32_16x16x32_f16(af[m], bfr[n], acc[m][n], 0, 0, 0);
    __syncthreads();
  }
  const int crow0 = brow + wr * 64 + ((lane >> 4) << 2);
  const int ccol0 = bcol + wc * 64 + (lane & 15);
#pragma unroll
  for (int m = 0; m < 4; ++m)
#pragma unroll
    for (int n = 0; n < 4; ++n)
#pragma unroll
      for (int r = 0; r < 4; ++r) {
        float* p = out + (size_t)(crow0 + m * 16 + r) * OUT_F + (ccol0 + n * 16);
        if constexpr (STREAM == 0) *p = (float)(f16)acc[m][n][r];
        else *p += acc[m][n][r];
      }
}

// ---------------------------------------------------------------------------
extern "C" void kernel_launch(void* const* d_in, const int* in_sizes, int n_in,
                              void* d_out, int out_size, void* d_ws, size_t ws_size,
                              hipStream_t stream) {
  const float* x    = (const float*)d_in[0];
  const float* W    = (const float*)d_in[1];
  const float* vals = (const float*)d_in[2];
  const int*   rows = (const int*)d_in[3];
  const int*   cols = (const int*)d_in[4];
  float*       out  = (float*)d_out;

  const i64 total_x = (i64)in_sizes[0];
  const int M   = (int)(total_x / IN_F);            // 8192
  const int nnz = in_sizes[2];
  if (M <= 0 || M % 128 != 0) return;

  const size_t whb = (size_t)OUT_F * IN_F * 2;      // 32 MB
  const size_t xhb = (size_t)M * IN_F * 2;          // 64 MB

  if (ws_size >= xhb + 2 * whb) {
    f16* xh  = (f16*)d_ws;
    f16* wh  = (f16*)((char*)d_ws + xhb);
    f16* woh = (f16*)((char*)d_ws + xhb + whb);
    cvt_f32_f16<<<2048, 256, 0, stream>>>(x, xh, total_x / 8);
    cvt_f32_f16<<<2048, 256, 0, stream>>>(W, wh, (i64)OUT_F * IN_F / 8);
    zero32<<<2048, 256, 0, stream>>>((u32*)woh, (i64)(whb / 4));
    scatter_woh<<<(nnz + 255) / 256, 256, 0, stream>>>(vals, rows, cols, woh, nnz);
    if (M % 256 == 0) {
      const int grid = (M / 256) * (OUT_F / 256);   // 512
      gemm_1k<0><<<grid, 1024, 0, stream>>>(xh, wh, out, M);
      gemm_1k<1><<<grid, 1024, 0, stream>>>(xh, woh, out, M);
    } else {
      const int grid = (M / 128) * (OUT_F / 128);
      gemm_one<true, 0><<<grid, 256, 0, stream>>>(nullptr, xh, wh, out, M);
      gemm_one<true, 1><<<grid, 256, 0, stream>>>(nullptr, xh, woh, out, M);
    }
  } else if (ws_size >= 2 * whb) {
    f16* wh  = (f16*)d_ws;
    f16* woh = (f16*)((char*)d_ws + whb);
    cvt_f32_f16<<<2048, 256, 0, stream>>>(W, wh, (i64)OUT_F * IN_F / 8);
    zero32<<<2048, 256, 0, stream>>>((u32*)woh, (i64)(whb / 4));
    scatter_woh<<<(nnz + 255) / 256, 256, 0, stream>>>(vals, rows, cols, woh, nnz);
    const int grid = (M / 128) * (OUT_F / 128);
    gemm_one<false, 0><<<grid, 256, 0, stream>>>(x, nullptr, wh, out, M);
    gemm_one<false, 1><<<grid, 256, 0, stream>>>(x, nullptr, woh, out, M);
  }
}

// Round 16
// 623.010 us; speedup vs baseline: 1.0417x; 1.0417x over previous
//
#include <hip/hip_runtime.h>

typedef _Float16 f16;
typedef unsigned short u16;
typedef unsigned int u32;
typedef long long i64;
typedef __attribute__((ext_vector_type(8))) _Float16 f16x8;
typedef __attribute__((ext_vector_type(4))) float f32x4;

#define IN_F 4096
#define OUT_F 4096

__device__ __forceinline__ void gload16(const f16* g, f16* l) {
  __builtin_amdgcn_global_load_lds(
      (const __attribute__((address_space(1))) void*)g,
      (__attribute__((address_space(3))) void*)l, 16, 0, 0);
}

// ---------------------------------------------------------------------------
// prep kernels
// ---------------------------------------------------------------------------
__global__ __launch_bounds__(256) void cvt_f32_f16(
    const float* __restrict__ in, f16* __restrict__ out, i64 n8) {
  i64 s = (i64)gridDim.x * blockDim.x;
  for (i64 j = (i64)blockIdx.x * blockDim.x + threadIdx.x; j < n8; j += s) {
    float4 a = ((const float4*)in)[2 * j];
    float4 b = ((const float4*)in)[2 * j + 1];
    f16x8 o;
    o[0] = (f16)a.x; o[1] = (f16)a.y; o[2] = (f16)a.z; o[3] = (f16)a.w;
    o[4] = (f16)b.x; o[5] = (f16)b.y; o[6] = (f16)b.z; o[7] = (f16)b.w;
    ((f16x8*)out)[j] = o;
  }
}

__global__ __launch_bounds__(256) void zero32(u32* __restrict__ p, i64 n) {
  i64 s = (i64)gridDim.x * blockDim.x;
  for (i64 j = (i64)blockIdx.x * blockDim.x + threadIdx.x; j < n; j += s) p[j] = 0u;
}

__global__ __launch_bounds__(256) void scatter_woh(
    const float* __restrict__ vals, const int* __restrict__ rows,
    const int* __restrict__ cols, f16* __restrict__ woh, int nnz) {
  int i = blockIdx.x * blockDim.x + threadIdx.x;
  if (i >= nnz) return;
  int r = rows[i], c = cols[i];
  if (r < 0 || r >= OUT_F || c < 0 || c >= IN_F) return;
  float v = vals[i];
  size_t idx = (size_t)r * IN_F + c;
  u32* p = (u32*)woh + (idx >> 1);
  u32 sh = (u32)(idx & 1) * 16u;
  union { f16 h; u16 u; } cv;
  u32 old = *p;
  while (true) {
    u32 assumed = old;
    cv.u = (u16)((assumed >> sh) & 0xFFFFu);
    float cur = (float)cv.h;
    cv.h = (f16)(cur + v);
    u32 nw = (assumed & ~(0xFFFFu << sh)) | ((u32)cv.u << sh);
    old = atomicCAS(p, assumed, nw);
    if (old == assumed) break;
  }
}

// ---------------------------------------------------------------------------
// 256x256 tile, BK=64, 8 waves (2Mx4N), UNBROKEN read+MFMA window per K-tile.
// Per tile: [24 ds_read_b128 + 64 MFMA, no barriers] -> Bend ->
// [issue 8 stages for tile t+2 into freed buffer] -> vmcnt(8) -> Bmid.
// Waves slip within the window so MFMA and LDS-read overlap across waves.
// T2 swizzle (pre-swizzled global src, lane-linear LDS dest), T5 setprio.
// STREAM 0: out = f32(f16(acc));  1: out += acc.
// ---------------------------------------------------------------------------
template <int STREAM>
__global__ __launch_bounds__(512, 2) void gemm_256(
    const f16* __restrict__ Xh, const f16* __restrict__ Bm,
    float* __restrict__ out, int M) {
  __shared__ alignas(16) f16 As[2][16384];
  __shared__ alignas(16) f16 Bs[2][16384];

  const int tid = threadIdx.x;
  const int lane = tid & 63;
  const int wave = tid >> 6;
  const int wr = wave >> 2;         // 0..1  (M half)
  const int wc = wave & 3;          // 0..3  (N quarter)
  const int lo = lane & 15, hi = lane >> 4, l7 = lane & 7;

  const int bid = (int)blockIdx.x;
  const int nbn = OUT_F / 256;                      // 16
  const int nwg = (M / 256) * nbn;
  const int swz = ((nwg & 7) == 0) ? ((bid & 7) * (nwg >> 3) + (bid >> 3)) : bid;
  const int brow = (swz / nbn) << 8;
  const int bcol = (swz % nbn) << 8;

  // staging chunks: c = i*512+tid; LDS dest = c*8 (lane-linear);
  // source row = c>>3, kchunk = (c&7)^(row&7)  [T2: pre-swizzled global src]
  int aglob[4], bglob[4], ldst[4];
#pragma unroll
  for (int i = 0; i < 4; ++i) {
    int c = i * 512 + tid;
    int row = c >> 3;
    int kc = (c & 7) ^ (row & 7);
    ldst[i] = c * 8;
    aglob[i] = (brow + row) * IN_F + kc * 8;
    bglob[i] = (bcol + row) * IN_F + kc * 8;
  }

  // fragment read offsets: row*64 + (((ks<<2)|hi) ^ (row&7))*8, row&7 == l7
  const int abase = (wr * 128 + lo) * 64;   // + mf*1024 + slot
  const int bbase = (wc * 64 + lo) * 64;    // + nf*1024 + slot
  const int slot0 = ((hi) ^ l7) * 8;        // ks=0
  const int slot1 = ((4 + hi) ^ l7) * 8;    // ks=1

  f32x4 acc[8][4] = {};

  // prologue: stage tile 0 -> buf0 (8 loads), tile 1 -> buf1 (8 loads)
#pragma unroll
  for (int i = 0; i < 4; ++i) {
    gload16(Xh + aglob[i], &As[0][ldst[i]]);
    gload16(Bm + bglob[i], &Bs[0][ldst[i]]);
  }
#pragma unroll
  for (int i = 0; i < 4; ++i) {
    gload16(Xh + aglob[i] + 64, &As[1][ldst[i]]);
    gload16(Bm + bglob[i] + 64, &Bs[1][ldst[i]]);
  }
  asm volatile("s_waitcnt vmcnt(8)" ::: "memory");  // tile 0 landed; tile 1 flies
  __builtin_amdgcn_sched_barrier(0);
  __builtin_amdgcn_s_barrier();

  const int NT = IN_F / 64;                 // 64
  for (int kt = 0; kt < NT; ++kt) {
    const f16* A = As[kt & 1];
    const f16* B = Bs[kt & 1];

    // ---- unbroken read + MFMA window (no barriers inside) ----
    f16x8 bf[4][2];
#pragma unroll
    for (int nf = 0; nf < 4; ++nf) {
      bf[nf][0] = *(const f16x8*)(B + bbase + nf * 1024 + slot0);
      bf[nf][1] = *(const f16x8*)(B + bbase + nf * 1024 + slot1);
    }
#pragma unroll
    for (int q = 0; q < 4; ++q) {
      f16x8 a00 = *(const f16x8*)(A + abase + (2 * q)     * 1024 + slot0);
      f16x8 a01 = *(const f16x8*)(A + abase + (2 * q)     * 1024 + slot1);
      f16x8 a10 = *(const f16x8*)(A + abase + (2 * q + 1) * 1024 + slot0);
      f16x8 a11 = *(const f16x8*)(A + abase + (2 * q + 1) * 1024 + slot1);
      __builtin_amdgcn_s_setprio(1);
#pragma unroll
      for (int nf = 0; nf < 4; ++nf) {
        acc[2 * q][nf]     = __builtin_amdgcn_mfma_f32_16x16x32_f16(a00, bf[nf][0], acc[2 * q][nf], 0, 0, 0);
        acc[2 * q][nf]     = __builtin_amdgcn_mfma_f32_16x16x32_f16(a01, bf[nf][1], acc[2 * q][nf], 0, 0, 0);
        acc[2 * q + 1][nf] = __builtin_amdgcn_mfma_f32_16x16x32_f16(a10, bf[nf][0], acc[2 * q + 1][nf], 0, 0, 0);
        acc[2 * q + 1][nf] = __builtin_amdgcn_mfma_f32_16x16x32_f16(a11, bf[nf][1], acc[2 * q + 1][nf], 0, 0, 0);
      }
      __builtin_amdgcn_s_setprio(0);
    }

    // ---- tile boundary ----
    __builtin_amdgcn_s_barrier();           // Bend: all reads of tile kt done
    if (kt + 2 < NT) {
      // stage tile kt+2 into the buffer tile kt occupied
      f16* An = (f16*)As[kt & 1];
      f16* Bn = (f16*)Bs[kt & 1];
      const int kn = (kt + 2) * 64;
#pragma unroll
      for (int i = 0; i < 4; ++i) {
        gload16(Xh + aglob[i] + kn, An + ldst[i]);
        gload16(Bm + bglob[i] + kn, Bn + ldst[i]);
      }
    }
    if (kt + 1 < NT) {
      if (kt + 2 < NT) asm volatile("s_waitcnt vmcnt(8)" ::: "memory");
      else             asm volatile("s_waitcnt vmcnt(0)" ::: "memory");
      __builtin_amdgcn_sched_barrier(0);
      __builtin_amdgcn_s_barrier();         // Bmid: tile kt+1 visible to all
    }
  }

  // epilogue.  C/D: col = lane&15, row = (lane>>4)*4 + r  (m89-verified)
  const int crow0 = brow + wr * 128 + (hi << 2);
  const int ccol0 = bcol + wc * 64 + lo;
#pragma unroll
  for (int mf = 0; mf < 8; ++mf)
#pragma unroll
    for (int nf = 0; nf < 4; ++nf)
#pragma unroll
      for (int r = 0; r < 4; ++r) {
        float* p = out + (size_t)(crow0 + mf * 16 + r) * OUT_F + (ccol0 + nf * 16);
        if constexpr (STREAM == 0)
          *p = (float)(f16)acc[mf][nf][r];
        else
          *p += acc[mf][nf][r];
      }
}

// ---------------------------------------------------------------------------
// R12 fallback (proven): 128x128, 2-barrier, reg-staged A from f32
// ---------------------------------------------------------------------------
template <bool A16, int STREAM>
__global__ __launch_bounds__(256, 2) void gemm_one(
    const float* __restrict__ Xf, const f16* __restrict__ Xh,
    const f16* __restrict__ Bm, float* __restrict__ out, int M) {
  constexpr int LDA = A16 ? 32 : 40;
  __shared__ alignas(16) f16 As[128 * LDA];
  __shared__ alignas(16) f16 Bs[128 * 32];

  const int tid = threadIdx.x, lane = tid & 63, wave = tid >> 6;
  const int wr = wave >> 1, wc = wave & 1;
  const int nbn = OUT_F / 128;
  const int nwg = (int)gridDim.x;
  const int bid = (int)blockIdx.x;
  const int swz = ((nwg & 7) == 0) ? ((bid & 7) * (nwg >> 3) + (bid >> 3)) : bid;
  const int brow = (swz / nbn) << 7;
  const int bcol = (swz % nbn) << 7;

  f32x4 acc[4][4] = {};
  const int srow = tid >> 2, sk = (tid & 3) * 8;
  const f16* gB = Bm + (size_t)(bcol + srow) * IN_F + sk;
  f16* sB = Bs + tid * 8;
  const f16*   gA = A16 ? (Xh + (size_t)(brow + srow) * IN_F + sk) : (const f16*)nullptr;
  const float* gX = A16 ? (const float*)nullptr : (Xf + (size_t)(brow + srow) * IN_F + sk);
  f16* sA  = As + tid * 8;
  f16* sAr = As + srow * LDA + sk;
  const f16* pa = As + (wr * 64 + (lane & 15)) * LDA + (lane >> 4) * 8;
  const f16* pb = Bs + (wc * 64 + (lane & 15)) * 32 + (lane >> 4) * 8;

  for (int k0 = 0; k0 < IN_F; k0 += 32) {
    if constexpr (A16) {
      gload16(gA + k0, sA);
      gload16(gA + k0 + (size_t)64 * IN_F, sA + 2048);
    } else {
      float4 u0 = *(const float4*)(gX + k0);
      float4 u1 = *(const float4*)(gX + k0 + 4);
      float4 v0 = *(const float4*)(gX + k0 + (size_t)64 * IN_F);
      float4 v1 = *(const float4*)(gX + k0 + (size_t)64 * IN_F + 4);
      f16x8 h0, h1;
      h0[0] = (f16)u0.x; h0[1] = (f16)u0.y; h0[2] = (f16)u0.z; h0[3] = (f16)u0.w;
      h0[4] = (f16)u1.x; h0[5] = (f16)u1.y; h0[6] = (f16)u1.z; h0[7] = (f16)u1.w;
      h1[0] = (f16)v0.x; h1[1] = (f16)v0.y; h1[2] = (f16)v0.z; h1[3] = (f16)v0.w;
      h1[4] = (f16)v1.x; h1[5] = (f16)v1.y; h1[6] = (f16)v1.z; h1[7] = (f16)v1.w;
      *(f16x8*)sAr = h0;
      *(f16x8*)(sAr + 64 * LDA) = h1;
    }
    gload16(gB + k0, sB);
    gload16(gB + k0 + (size_t)64 * IN_F, sB + 2048);
    __syncthreads();
    f16x8 af[4], bfr[4];
#pragma unroll
    for (int m = 0; m < 4; ++m) af[m] = *(const f16x8*)(pa + m * 16 * LDA);
#pragma unroll
    for (int n = 0; n < 4; ++n) bfr[n] = *(const f16x8*)(pb + n * 512);
#pragma unroll
    for (int m = 0; m < 4; ++m)
#pragma unroll
      for (int n = 0; n < 4; ++n)
        acc[m][n] = __builtin_amdgcn_mfma_f32_16x16x32_f16(af[m], bfr[n], acc[m][n], 0, 0, 0);
    __syncthreads();
  }
  const int crow0 = brow + wr * 64 + ((lane >> 4) << 2);
  const int ccol0 = bcol + wc * 64 + (lane & 15);
#pragma unroll
  for (int m = 0; m < 4; ++m)
#pragma unroll
    for (int n = 0; n < 4; ++n)
#pragma unroll
      for (int r = 0; r < 4; ++r) {
        float* p = out + (size_t)(crow0 + m * 16 + r) * OUT_F + (ccol0 + n * 16);
        if constexpr (STREAM == 0) *p = (float)(f16)acc[m][n][r];
        else *p += acc[m][n][r];
      }
}

// ---------------------------------------------------------------------------
extern "C" void kernel_launch(void* const* d_in, const int* in_sizes, int n_in,
                              void* d_out, int out_size, void* d_ws, size_t ws_size,
                              hipStream_t stream) {
  const float* x    = (const float*)d_in[0];
  const float* W    = (const float*)d_in[1];
  const float* vals = (const float*)d_in[2];
  const int*   rows = (const int*)d_in[3];
  const int*   cols = (const int*)d_in[4];
  float*       out  = (float*)d_out;

  const i64 total_x = (i64)in_sizes[0];
  const int M   = (int)(total_x / IN_F);            // 8192
  const int nnz = in_sizes[2];
  if (M <= 0 || M % 128 != 0) return;

  const size_t whb = (size_t)OUT_F * IN_F * 2;      // 32 MB
  const size_t xhb = (size_t)M * IN_F * 2;          // 64 MB

  if (ws_size >= xhb + 2 * whb) {
    f16* xh  = (f16*)d_ws;
    f16* wh  = (f16*)((char*)d_ws + xhb);
    f16* woh = (f16*)((char*)d_ws + xhb + whb);
    cvt_f32_f16<<<2048, 256, 0, stream>>>(x, xh, total_x / 8);
    cvt_f32_f16<<<2048, 256, 0, stream>>>(W, wh, (i64)OUT_F * IN_F / 8);
    zero32<<<2048, 256, 0, stream>>>((u32*)woh, (i64)(whb / 4));
    scatter_woh<<<(nnz + 255) / 256, 256, 0, stream>>>(vals, rows, cols, woh, nnz);
    if (M % 256 == 0) {
      const int grid = (M / 256) * (OUT_F / 256);   // 512
      gemm_256<0><<<grid, 512, 0, stream>>>(xh, wh, out, M);
      gemm_256<1><<<grid, 512, 0, stream>>>(xh, woh, out, M);
    } else {
      const int grid = (M / 128) * (OUT_F / 128);
      gemm_one<true, 0><<<grid, 256, 0, stream>>>(nullptr, xh, wh, out, M);
      gemm_one<true, 1><<<grid, 256, 0, stream>>>(nullptr, xh, woh, out, M);
    }
  } else if (ws_size >= 2 * whb) {
    f16* wh  = (f16*)d_ws;
    f16* woh = (f16*)((char*)d_ws + whb);
    cvt_f32_f16<<<2048, 256, 0, stream>>>(W, wh, (i64)OUT_F * IN_F / 8);
    zero32<<<2048, 256, 0, stream>>>((u32*)woh, (i64)(whb / 4));
    scatter_woh<<<(nnz + 255) / 256, 256, 0, stream>>>(vals, rows, cols, woh, nnz);
    const int grid = (M / 128) * (OUT_F / 128);
    gemm_one<false, 0><<<grid, 256, 0, stream>>>(x, nullptr, wh, out, M);
    gemm_one<false, 1><<<grid, 256, 0, stream>>>(x, nullptr, woh, out, M);
  }
}

// Round 18
// 556.535 us; speedup vs baseline: 1.1661x; 1.1194x over previous
//
#include <hip/hip_runtime.h>

typedef _Float16 f16;
typedef unsigned short u16;
typedef unsigned int u32;
typedef long long i64;
typedef __attribute__((ext_vector_type(8))) _Float16 f16x8;
typedef __attribute__((ext_vector_type(4))) float f32x4;

#define IN_F 4096
#define OUT_F 4096

__device__ __forceinline__ void gload16(const f16* g, f16* l) {
  __builtin_amdgcn_global_load_lds(
      (const __attribute__((address_space(1))) void*)g,
      (__attribute__((address_space(3))) void*)l, 16, 0, 0);
}

// ---------------------------------------------------------------------------
// prep kernels
// ---------------------------------------------------------------------------
__global__ __launch_bounds__(256) void cvt_f32_f16(
    const float* __restrict__ in, f16* __restrict__ out, i64 n8) {
  i64 s = (i64)gridDim.x * blockDim.x;
  for (i64 j = (i64)blockIdx.x * blockDim.x + threadIdx.x; j < n8; j += s) {
    float4 a = ((const float4*)in)[2 * j];
    float4 b = ((const float4*)in)[2 * j + 1];
    f16x8 o;
    o[0] = (f16)a.x; o[1] = (f16)a.y; o[2] = (f16)a.z; o[3] = (f16)a.w;
    o[4] = (f16)b.x; o[5] = (f16)b.y; o[6] = (f16)b.z; o[7] = (f16)b.w;
    ((f16x8*)out)[j] = o;
  }
}

__global__ __launch_bounds__(256) void zero32(u32* __restrict__ p, i64 n) {
  i64 s = (i64)gridDim.x * blockDim.x;
  for (i64 j = (i64)blockIdx.x * blockDim.x + threadIdx.x; j < n; j += s) p[j] = 0u;
}

__global__ __launch_bounds__(256) void scatter_woh(
    const float* __restrict__ vals, const int* __restrict__ rows,
    const int* __restrict__ cols, f16* __restrict__ woh, int nnz) {
  int i = blockIdx.x * blockDim.x + threadIdx.x;
  if (i >= nnz) return;
  int r = rows[i], c = cols[i];
  if (r < 0 || r >= OUT_F || c < 0 || c >= IN_F) return;
  float v = vals[i];
  size_t idx = (size_t)r * IN_F + c;
  u32* p = (u32*)woh + (idx >> 1);
  u32 sh = (u32)(idx & 1) * 16u;
  union { f16 h; u16 u; } cv;
  u32 old = *p;
  while (true) {
    u32 assumed = old;
    cv.u = (u16)((assumed >> sh) & 0xFFFFu);
    float cur = (float)cv.h;
    cv.h = (f16)(cur + v);
    u32 nw = (assumed & ~(0xFFFFu << sh)) | ((u32)cv.u << sh);
    old = atomicCAS(p, assumed, nw);
    if (old == assumed) break;
  }
}

// ---------------------------------------------------------------------------
// 256x256 8-phase GEMM (R14 schedule) + R18 edits:
//  (i) ks-outer MFMA order per phase (same-acc dependency distance 1 -> 8)
//  (ii) XCD 8x8 panel grouping (FIXED, bijective, gated to nbm==32 && nbn==16):
//       browi = (xcd&3)*8 + jr in [0,32);  bcoli = (xcd>>2)*8 + jc in [0,16).
//       Inverse: xcd = (bcoli>>3)*4 + (browi>>3), jr = browi&7, jc = bcoli&7.
// T2 swizzle, counted vmcnt (T4), T5 setprio.
// STREAM 0: out = f32(f16(acc));  1: out += acc.
// ---------------------------------------------------------------------------
template <int STREAM>
__global__ __launch_bounds__(512, 2) void gemm_256(
    const f16* __restrict__ Xh, const f16* __restrict__ Bm,
    float* __restrict__ out, int M) {
  __shared__ alignas(16) f16 As[2][16384];
  __shared__ alignas(16) f16 Bs[2][16384];

  const int tid = threadIdx.x;
  const int lane = tid & 63;
  const int wave = tid >> 6;
  const int wr = wave >> 2;         // 0..1  (M half)
  const int wc = wave & 3;          // 0..3  (N quarter)
  const int lo = lane & 15, hi = lane >> 4, l7 = lane & 7;

  const int bid = (int)blockIdx.x;
  const int nbn = OUT_F / 256;                      // 16
  const int nbm = M / 256;
  int browi, bcoli;
  if (nbm == 32 && nbn == 16) {
    // (ii) fixed 8x8 panel per XCD
    const int xcd = bid & 7;
    const int j   = bid >> 3;                       // 0..63
    const int jr  = j >> 3, jc = j & 7;
    browi = (xcd & 3) * 8 + jr;                     // [0,32)
    bcoli = (xcd >> 2) * 8 + jc;                    // [0,16)
  } else {
    const int nwg = nbm * nbn;
    const int swz = ((nwg & 7) == 0) ? ((bid & 7) * (nwg >> 3) + (bid >> 3)) : bid;
    browi = swz / nbn;
    bcoli = swz % nbn;
  }
  const int brow = browi << 8;
  const int bcol = bcoli << 8;

  // staging chunks: c = i*512+tid; LDS dest = c*8 (lane-linear);
  // source row = c>>3, kchunk = (c&7)^(row&7)  [T2: pre-swizzled global src]
  int aglob[4], bglob[4], ldst[4];
#pragma unroll
  for (int i = 0; i < 4; ++i) {
    int c = i * 512 + tid;
    int row = c >> 3;
    int kc = (c & 7) ^ (row & 7);
    ldst[i] = c * 8;
    aglob[i] = (brow + row) * IN_F + kc * 8;
    bglob[i] = (bcol + row) * IN_F + kc * 8;
  }

  // fragment read offsets: row*64 + (((ks<<2)|hi) ^ (row&7))*8, row&7 == l7
  const int abase = (wr * 128 + lo) * 64;   // + mf*1024 + slot
  const int bbase = (wc * 64 + lo) * 64;    // + nf*1024 + slot
  const int slot0 = ((hi) ^ l7) * 8;        // ks=0
  const int slot1 = ((4 + hi) ^ l7) * 8;    // ks=1

  f32x4 acc[8][4] = {};

  // prologue: stage tile 0 -> buf 0 in steady-state order
  gload16(Bm + bglob[0], &Bs[0][ldst[0]]);
  gload16(Bm + bglob[1], &Bs[0][ldst[1]]);
  gload16(Bm + bglob[2], &Bs[0][ldst[2]]);
  gload16(Bm + bglob[3], &Bs[0][ldst[3]]);
  gload16(Xh + aglob[0], &As[0][ldst[0]]);
  gload16(Xh + aglob[2], &As[0][ldst[2]]);
  gload16(Xh + aglob[1], &As[0][ldst[1]]);
  gload16(Xh + aglob[3], &As[0][ldst[3]]);
  asm volatile("s_waitcnt vmcnt(2)" ::: "memory");  // B0-3,A0,A2 landed; A1,A3 fly
  __builtin_amdgcn_sched_barrier(0);
  __builtin_amdgcn_s_barrier();

  // (i) ks-outer MFMA cluster: consecutive instrs hit different accumulators
#define MFMA_CLUSTER(base)                                                        \
  __builtin_amdgcn_s_setprio(1);                                                  \
  _Pragma("unroll")                                                               \
  for (int ks = 0; ks < 2; ++ks)                                                  \
    _Pragma("unroll")                                                             \
    for (int mm = 0; mm < 2; ++mm)                                                \
      _Pragma("unroll")                                                           \
      for (int nf = 0; nf < 4; ++nf)                                              \
        acc[(base) + mm][nf] = __builtin_amdgcn_mfma_f32_16x16x32_f16(            \
            af[mm][ks], bf[nf][ks], acc[(base) + mm][nf], 0, 0, 0);               \
  __builtin_amdgcn_s_setprio(0);

  const int NT = IN_F / 64;                 // 64
  for (int kt = 0; kt < NT; ++kt) {
    const f16* A = As[kt & 1];
    const f16* B = Bs[kt & 1];
    f16* An = (f16*)As[(kt & 1) ^ 1];
    f16* Bn = (f16*)Bs[(kt & 1) ^ 1];
    const int kn = (kt + 1) * 64;
    const bool pf = (kt + 1 < NT);

    f16x8 bf[4][2];
    f16x8 af[2][2];

    // ---- phase 1: read B-all + A mf0,1 | stage B chunks 0,1
#pragma unroll
    for (int nf = 0; nf < 4; ++nf) {
      bf[nf][0] = *(const f16x8*)(B + bbase + nf * 1024 + slot0);
      bf[nf][1] = *(const f16x8*)(B + bbase + nf * 1024 + slot1);
    }
    af[0][0] = *(const f16x8*)(A + abase + 0 * 1024 + slot0);
    af[0][1] = *(const f16x8*)(A + abase + 0 * 1024 + slot1);
    af[1][0] = *(const f16x8*)(A + abase + 1 * 1024 + slot0);
    af[1][1] = *(const f16x8*)(A + abase + 1 * 1024 + slot1);
    if (pf) { gload16(Bm + bglob[0] + kn, Bn + ldst[0]);
              gload16(Bm + bglob[1] + kn, Bn + ldst[1]); }
    __builtin_amdgcn_s_barrier();
    MFMA_CLUSTER(0)
    __builtin_amdgcn_s_barrier();

    // ---- phase 2: read A mf2,3 | stage B chunks 2,3 | gate A{1,3}
    af[0][0] = *(const f16x8*)(A + abase + 2 * 1024 + slot0);
    af[0][1] = *(const f16x8*)(A + abase + 2 * 1024 + slot1);
    af[1][0] = *(const f16x8*)(A + abase + 3 * 1024 + slot0);
    af[1][1] = *(const f16x8*)(A + abase + 3 * 1024 + slot1);
    if (pf) { gload16(Bm + bglob[2] + kn, Bn + ldst[2]);
              gload16(Bm + bglob[3] + kn, Bn + ldst[3]); }
    if (pf) asm volatile("s_waitcnt vmcnt(4)" ::: "memory");
    else    asm volatile("s_waitcnt vmcnt(0)" ::: "memory");
    __builtin_amdgcn_sched_barrier(0);
    __builtin_amdgcn_s_barrier();
    MFMA_CLUSTER(2)
    __builtin_amdgcn_s_barrier();

    // ---- phase 3: read A mf4,5 | stage A chunks 0,2
    af[0][0] = *(const f16x8*)(A + abase + 4 * 1024 + slot0);
    af[0][1] = *(const f16x8*)(A + abase + 4 * 1024 + slot1);
    af[1][0] = *(const f16x8*)(A + abase + 5 * 1024 + slot0);
    af[1][1] = *(const f16x8*)(A + abase + 5 * 1024 + slot1);
    if (pf) { gload16(Xh + aglob[0] + kn, An + ldst[0]);
              gload16(Xh + aglob[2] + kn, An + ldst[2]); }
    __builtin_amdgcn_s_barrier();
    MFMA_CLUSTER(4)
    __builtin_amdgcn_s_barrier();

    // ---- phase 4: read A mf6,7 | stage A chunks 1,3 | gate next ph1/ph2
    af[0][0] = *(const f16x8*)(A + abase + 6 * 1024 + slot0);
    af[0][1] = *(const f16x8*)(A + abase + 6 * 1024 + slot1);
    af[1][0] = *(const f16x8*)(A + abase + 7 * 1024 + slot0);
    af[1][1] = *(const f16x8*)(A + abase + 7 * 1024 + slot1);
    if (pf) { gload16(Xh + aglob[1] + kn, An + ldst[1]);
              gload16(Xh + aglob[3] + kn, An + ldst[3]); }
    if (pf) {
      asm volatile("s_waitcnt vmcnt(2)" ::: "memory");  // A{1,3} stay in flight
      __builtin_amdgcn_sched_barrier(0);
    }
    __builtin_amdgcn_s_barrier();
    MFMA_CLUSTER(6)
    __builtin_amdgcn_s_barrier();
  }
#undef MFMA_CLUSTER

  // epilogue.  C/D: col = lane&15, row = (lane>>4)*4 + r
  const int crow0 = brow + wr * 128 + (hi << 2);
  const int ccol0 = bcol + wc * 64 + lo;
#pragma unroll
  for (int mf = 0; mf < 8; ++mf)
#pragma unroll
    for (int nf = 0; nf < 4; ++nf)
#pragma unroll
      for (int r = 0; r < 4; ++r) {
        float* p = out + (size_t)(crow0 + mf * 16 + r) * OUT_F + (ccol0 + nf * 16);
        if constexpr (STREAM == 0)
          *p = (float)(f16)acc[mf][nf][r];
        else
          *p += acc[mf][nf][r];
      }
}

// ---------------------------------------------------------------------------
// R12 fallback (proven): 128x128, 2-barrier, reg-staged A from f32
// ---------------------------------------------------------------------------
template <bool A16, int STREAM>
__global__ __launch_bounds__(256, 2) void gemm_one(
    const float* __restrict__ Xf, const f16* __restrict__ Xh,
    const f16* __restrict__ Bm, float* __restrict__ out, int M) {
  constexpr int LDA = A16 ? 32 : 40;
  __shared__ alignas(16) f16 As[128 * LDA];
  __shared__ alignas(16) f16 Bs[128 * 32];

  const int tid = threadIdx.x, lane = tid & 63, wave = tid >> 6;
  const int wr = wave >> 1, wc = wave & 1;
  const int nbn = OUT_F / 128;
  const int nwg = (int)gridDim.x;
  const int bid = (int)blockIdx.x;
  const int swz = ((nwg & 7) == 0) ? ((bid & 7) * (nwg >> 3) + (bid >> 3)) : bid;
  const int brow = (swz / nbn) << 7;
  const int bcol = (swz % nbn) << 7;

  f32x4 acc[4][4] = {};
  const int srow = tid >> 2, sk = (tid & 3) * 8;
  const f16* gB = Bm + (size_t)(bcol + srow) * IN_F + sk;
  f16* sB = Bs + tid * 8;
  const f16*   gA = A16 ? (Xh + (size_t)(brow + srow) * IN_F + sk) : (const f16*)nullptr;
  const float* gX = A16 ? (const float*)nullptr : (Xf + (size_t)(brow + srow) * IN_F + sk);
  f16* sA  = As + tid * 8;
  f16* sAr = As + srow * LDA + sk;
  const f16* pa = As + (wr * 64 + (lane & 15)) * LDA + (lane >> 4) * 8;
  const f16* pb = Bs + (wc * 64 + (lane & 15)) * 32 + (lane >> 4) * 8;

  for (int k0 = 0; k0 < IN_F; k0 += 32) {
    if constexpr (A16) {
      gload16(gA + k0, sA);
      gload16(gA + k0 + (size_t)64 * IN_F, sA + 2048);
    } else {
      float4 u0 = *(const float4*)(gX + k0);
      float4 u1 = *(const float4*)(gX + k0 + 4);
      float4 v0 = *(const float4*)(gX + k0 + (size_t)64 * IN_F);
      float4 v1 = *(const float4*)(gX + k0 + (size_t)64 * IN_F + 4);
      f16x8 h0, h1;
      h0[0] = (f16)u0.x; h0[1] = (f16)u0.y; h0[2] = (f16)u0.z; h0[3] = (f16)u0.w;
      h0[4] = (f16)u1.x; h0[5] = (f16)u1.y; h0[6] = (f16)u1.z; h0[7] = (f16)u1.w;
      h1[0] = (f16)v0.x; h1[1] = (f16)v0.y; h1[2] = (f16)v0.z; h1[3] = (f16)v0.w;
      h1[4] = (f16)v1.x; h1[5] = (f16)v1.y; h1[6] = (f16)v1.z; h1[7] = (f16)v1.w;
      *(f16x8*)sAr = h0;
      *(f16x8*)(sAr + 64 * LDA) = h1;
    }
    gload16(gB + k0, sB);
    gload16(gB + k0 + (size_t)64 * IN_F, sB + 2048);
    __syncthreads();
    f16x8 af[4], bfr[4];
#pragma unroll
    for (int m = 0; m < 4; ++m) af[m] = *(const f16x8*)(pa + m * 16 * LDA);
#pragma unroll
    for (int n = 0; n < 4; ++n) bfr[n] = *(const f16x8*)(pb + n * 512);
#pragma unroll
    for (int m = 0; m < 4; ++m)
#pragma unroll
      for (int n = 0; n < 4; ++n)
        acc[m][n] = __builtin_amdgcn_mfma_f32_16x16x32_f16(af[m], bfr[n], acc[m][n], 0, 0, 0);
    __syncthreads();
  }
  const int crow0 = brow + wr * 64 + ((lane >> 4) << 2);
  const int ccol0 = bcol + wc * 64 + (lane & 15);
#pragma unroll
  for (int m = 0; m < 4; ++m)
#pragma unroll
    for (int n = 0; n < 4; ++n)
#pragma unroll
      for (int r = 0; r < 4; ++r) {
        float* p = out + (size_t)(crow0 + m * 16 + r) * OUT_F + (ccol0 + n * 16);
        if constexpr (STREAM == 0) *p = (float)(f16)acc[m][n][r];
        else *p += acc[m][n][r];
      }
}

// ---------------------------------------------------------------------------
extern "C" void kernel_launch(void* const* d_in, const int* in_sizes, int n_in,
                              void* d_out, int out_size, void* d_ws, size_t ws_size,
                              hipStream_t stream) {
  const float* x    = (const float*)d_in[0];
  const float* W    = (const float*)d_in[1];
  const float* vals = (const float*)d_in[2];
  const int*   rows = (const int*)d_in[3];
  const int*   cols = (const int*)d_in[4];
  float*       out  = (float*)d_out;

  const i64 total_x = (i64)in_sizes[0];
  const int M   = (int)(total_x / IN_F);            // 8192
  const int nnz = in_sizes[2];
  if (M <= 0 || M % 128 != 0) return;

  const size_t whb = (size_t)OUT_F * IN_F * 2;      // 32 MB
  const size_t xhb = (size_t)M * IN_F * 2;          // 64 MB

  if (ws_size >= xhb + 2 * whb) {
    f16* xh  = (f16*)d_ws;
    f16* wh  = (f16*)((char*)d_ws + xhb);
    f16* woh = (f16*)((char*)d_ws + xhb + whb);
    cvt_f32_f16<<<2048, 256, 0, stream>>>(x, xh, total_x / 8);
    cvt_f32_f16<<<2048, 256, 0, stream>>>(W, wh, (i64)OUT_F * IN_F / 8);
    zero32<<<2048, 256, 0, stream>>>((u32*)woh, (i64)(whb / 4));
    scatter_woh<<<(nnz + 255) / 256, 256, 0, stream>>>(vals, rows, cols, woh, nnz);
    if (M % 256 == 0) {
      const int grid = (M / 256) * (OUT_F / 256);   // 512
      gemm_256<0><<<grid, 512, 0, stream>>>(xh, wh, out, M);
      gemm_256<1><<<grid, 512, 0, stream>>>(xh, woh, out, M);
    } else {
      const int grid = (M / 128) * (OUT_F / 128);
      gemm_one<true, 0><<<grid, 256, 0, stream>>>(nullptr, xh, wh, out, M);
      gemm_one<true, 1><<<grid, 256, 0, stream>>>(nullptr, xh, woh, out, M);
    }
  } else if (ws_size >= 2 * whb) {
    f16* wh  = (f16*)d_ws;
    f16* woh = (f16*)((char*)d_ws + whb);
    cvt_f32_f16<<<2048, 256, 0, stream>>>(W, wh, (i64)OUT_F * IN_F / 8);
    zero32<<<2048, 256, 0, stream>>>((u32*)woh, (i64)(whb / 4));
    scatter_woh<<<(nnz + 255) / 256, 256, 0, stream>>>(vals, rows, cols, woh, nnz);
    const int grid = (M / 128) * (OUT_F / 128);
    gemm_one<false, 0><<<grid, 256, 0, stream>>>(x, nullptr, wh, out, M);
    gemm_one<false, 1><<<grid, 256, 0, stream>>>(x, nullptr, woh, out, M);
  }
}